// Round 11
// baseline (207.514 us; speedup 1.0000x reference)
//
#include <hip/hip_runtime.h>
#include <math.h>

// Problem constants
#define T_DIM 8192
#define N_DIM 4096
#define L 64
#define P 32
#define IN_DIM 192
#define S_CHUNK 16
#define N_CHUNK (T_DIM / S_CHUNK)   // 512
#define LDST 68                     // padded LDS row stride (float4-aligned)

using f32x4   = __attribute__((ext_vector_type(4))) float;
using bf16x8  = __attribute__((ext_vector_type(8))) short;
using ushort8 = __attribute__((ext_vector_type(8))) unsigned short;

__device__ __forceinline__ unsigned short f2bf(float x) {
  unsigned u = __float_as_uint(x);
  u += 0x7fffu + ((u >> 16) & 1u);           // round-to-nearest-even
  return (unsigned short)(u >> 16);
}
__device__ __forceinline__ float bf2f(unsigned short h) {
  return __uint_as_float(((unsigned)h) << 16);
}

// Packed fragment layout (both X and U):
//   pk[tile16][g][lane] = 8 bf16 of row (tile16*16 + lane), k-chunk g
//   g in 0..15: g<8 -> hi bits of k=8g..; g>=8 -> lo residual.
// One wave fragment load = contiguous 1 KiB (4 x 256 B groups) from L2.
__device__ __forceinline__ bf16x8 ldfrag(const unsigned short* __restrict__ base,
                                         int tile16, int gb, int lg, int lr) {
  return *(const bf16x8*)(base + ((size_t)((tile16 * 16 + gb + lg) * 16 + lr)) * 8);
}

#define MFMA(A, B, C) __builtin_amdgcn_mfma_f32_16x16x32_bf16(A, B, C, 0, 0, 0)

// ---------------- kernel A (merged): xh0 partials + U split + scratch init ----------------
__global__ __launch_bounds__(256) void k_init(const float* __restrict__ U,
                                              const float* __restrict__ Xtr,
                                              float* __restrict__ part,
                                              double* __restrict__ acc,
                                              int* __restrict__ cnt,
                                              unsigned short* __restrict__ upk) {
  int blk = blockIdx.x, tid = threadIdx.x;
  if (blk < 16) {
    if (blk == 0) {
      if (tid < 2) acc[tid] = 0.0;
      if (tid == 2) *cnt = 0;
    }
    int b = blk * 4 + (tid >> 6);
    int l = tid & 63;
    int n0 = b * 64;
    float s = 0.f;
    #pragma unroll 8
    for (int i = 0; i < 64; ++i) {
      float x = Xtr[n0 + i];
      s += U[(size_t)(n0 + i) * L + l] * x;
    }
    part[b * 64 + l] = s;
  } else {
    int idx = (blk - 16) * 256 + tid;         // 0 .. 65535
    int lr = idx & 15, g = (idx >> 4) & 15, nn16 = idx >> 8;
    int n = nn16 * 16 + lr;
    int k0 = (g & 7) * 8;
    float4 a = *(const float4*)(U + (size_t)n * L + k0);
    float4 b = *(const float4*)(U + (size_t)n * L + k0 + 4);
    ushort8 o;
    float v[8] = {a.x, a.y, a.z, a.w, b.x, b.y, b.z, b.w};
    #pragma unroll
    for (int j = 0; j < 8; ++j) {
      unsigned short h = f2bf(v[j]);
      o[j] = (g < 8) ? h : f2bf(v[j] - bf2f(h));
    }
    *(ushort8*)(upk + (size_t)idx * 8) = o;
  }
}

// ---------------- kernel B: argmax, temp, build M, xh0, matrix doublings ----------------
__global__ __launch_bounds__(256, 1) void k_prep(const float* __restrict__ A_tilde,
                                                 const float* __restrict__ phi_bar_t,
                                                 const float* __restrict__ logits,
                                                 const float* __restrict__ temp,
                                                 const float* __restrict__ part,
                                                 float* __restrict__ Wm,
                                                 float* __restrict__ xh0,
                                                 float* __restrict__ out_tail) {
  __shared__ float buf[2][64 * LDST];   // 34816 B
  __shared__ float sphi[P * L];         // 8192 B
  __shared__ float spart[4 * 64];       // 1024 B
  __shared__ int   sel_s[P];
  int tid = threadIdx.x;

  #pragma unroll
  for (int i = 0; i < 4; ++i) {
    int f = tid + 256 * i;
    int r = f >> 4, q = f & 15;
    float4 v = ((const float4*)A_tilde)[f];
    *(float4*)(buf[0] + r * LDST + q * 4) = v;
  }
  #pragma unroll
  for (int i = 0; i < 2; ++i) {
    int f = tid + 256 * i;
    ((float4*)sphi)[f] = ((const float4*)phi_bar_t)[f];
  }
  {
    int l = tid & 63, q = tid >> 6;
    float s = 0.f;
    #pragma unroll
    for (int i = 0; i < 16; ++i)
      s += part[(q * 16 + i) * 64 + l];
    spart[q * 64 + l] = s;
  }
  {
    int p = tid >> 3, d = tid & 7;
    const float* row = logits + p * IN_DIM;
    float best = -1e30f; int bk = 0;
    #pragma unroll
    for (int j = 0; j < 6; ++j) {
      int kb = (j * 8 + d) * 4;
      float4 v = *(const float4*)(row + kb);
      if (v.x > best) { best = v.x; bk = kb; }
      if (v.y > best) { best = v.y; bk = kb + 1; }
      if (v.z > best) { best = v.z; bk = kb + 2; }
      if (v.w > best) { best = v.w; bk = kb + 3; }
    }
    #pragma unroll
    for (int off = 4; off > 0; off >>= 1) {
      float vo = __shfl_down(best, off, 8);
      int   ko = __shfl_down(bk,   off, 8);
      if (vo > best || (vo == best && ko < bk)) { best = vo; bk = ko; }
    }
    if (d == 0) {
      sel_s[p] = bk;
      out_tail[2 + p] = (float)bk;
    }
  }
  if (tid == 255) out_tail[1] = fmaxf(0.01f, temp[0] * 0.999f);
  __syncthreads();

  if (tid < L) {
    #pragma unroll 4
    for (int p = 0; p < P; ++p) {
      int kk = sel_s[p]; if (kk > L - 1) kk = L - 1;
      buf[0][tid * LDST + kk] += sphi[p * L + tid];
    }
  } else if (tid < 128) {
    int l = tid - 64;
    xh0[l] = spart[l] + spart[64 + l] + spart[128 + l] + spart[192 + l];
  }
  __syncthreads();

  #pragma unroll
  for (int i = 0; i < 4; ++i) {
    int f = tid + 256 * i;
    int r = f >> 4, q = f & 15;
    *(float4*)(Wm + r * 64 + q * 4) = *(const float4*)(buf[0] + r * LDST + q * 4);
  }

  int r0 = (tid >> 4) << 2;
  int c0 = (tid & 15) << 2;
  int cur = 0;
  for (int j = 1; j <= 12; ++j) {
    const float* S = buf[cur];
    float* D = buf[cur ^ 1];
    float acc[4][4];
    #pragma unroll
    for (int i = 0; i < 4; ++i)
      #pragma unroll
      for (int c = 0; c < 4; ++c) acc[i][c] = 0.f;

    #pragma unroll
    for (int kb = 0; kb < 64; kb += 16) {
      float a[4][16];
      #pragma unroll
      for (int i = 0; i < 4; ++i)
        #pragma unroll
        for (int q = 0; q < 4; ++q) {
          float4 t4 = *(const float4*)(S + (r0 + i) * LDST + kb + q * 4);
          a[i][q * 4 + 0] = t4.x; a[i][q * 4 + 1] = t4.y;
          a[i][q * 4 + 2] = t4.z; a[i][q * 4 + 3] = t4.w;
        }
      #pragma unroll
      for (int kk = 0; kk < 16; ++kk) {
        float4 b4 = *(const float4*)(S + (kb + kk) * LDST + c0);
        #pragma unroll
        for (int i = 0; i < 4; ++i) {
          acc[i][0] += a[i][kk] * b4.x;
          acc[i][1] += a[i][kk] * b4.y;
          acc[i][2] += a[i][kk] * b4.z;
          acc[i][3] += a[i][kk] * b4.w;
        }
      }
    }
    #pragma unroll
    for (int i = 0; i < 4; ++i) {
      float4 o = {acc[i][0], acc[i][1], acc[i][2], acc[i][3]};
      *(float4*)(D + (r0 + i) * LDST + c0) = o;
      *(float4*)(Wm + j * 4096 + (r0 + i) * 64 + c0) = o;
    }
    __syncthreads();
    cur ^= 1;
  }
}

// ---------------- kernel C: states via checkpoints; emit PACKED bf16 hi/lo frags ----------------
__global__ __launch_bounds__(64) void k_states(const float* __restrict__ Wm,
                                               const float* __restrict__ xh0,
                                               unsigned short* __restrict__ xpk) {
  __shared__ float sx[16 * LDST];
  int c = blockIdx.x;
  int l = threadIdx.x;
  float v = xh0[l];
  int e = c << 4;
  for (int j = 4; j <= 12; ++j) {
    if ((e >> j) & 1) {
      const float* W = Wm + j * 4096;
      float n0 = 0.f, n1 = 0.f, n2 = 0.f, n3 = 0.f;
      #pragma unroll
      for (int k = 0; k < 64; k += 4) {
        n0 += W[l * 64 + k]     * __shfl(v, k, 64);
        n1 += W[l * 64 + k + 1] * __shfl(v, k + 1, 64);
        n2 += W[l * 64 + k + 2] * __shfl(v, k + 2, 64);
        n3 += W[l * 64 + k + 3] * __shfl(v, k + 3, 64);
      }
      v = (n0 + n1) + (n2 + n3);
    }
  }
  float m[64];
  #pragma unroll
  for (int k = 0; k < 64; ++k) m[k] = Wm[l * 64 + k];
  for (int i = 0; i < S_CHUNK; ++i) {
    float n0 = 0.f, n1 = 0.f, n2 = 0.f, n3 = 0.f;
    #pragma unroll
    for (int k = 0; k < 64; k += 4) {
      n0 += m[k]     * __shfl(v, k, 64);
      n1 += m[k + 1] * __shfl(v, k + 1, 64);
      n2 += m[k + 2] * __shfl(v, k + 2, 64);
      n3 += m[k + 3] * __shfl(v, k + 3, 64);
    }
    v = (n0 + n1) + (n2 + n3);
    sx[i * LDST + l] = v;
  }
  __syncthreads();

  #pragma unroll
  for (int it = 0; it < 4; ++it) {
    int idx = l + 64 * it;
    int lr = idx & 15, g = idx >> 4;
    int k0 = (g & 7) * 8;
    float4 a = *(const float4*)(sx + lr * LDST + k0);
    float4 b = *(const float4*)(sx + lr * LDST + k0 + 4);
    float vv[8] = {a.x, a.y, a.z, a.w, b.x, b.y, b.z, b.w};
    ushort8 o;
    #pragma unroll
    for (int j = 0; j < 8; ++j) {
      unsigned short h = f2bf(vv[j]);
      o[j] = (g < 8) ? h : f2bf(vv[j] - bf2f(h));
    }
    *(ushort8*)(xpk + ((size_t)c * 256 + idx) * 8) = o;
  }
}

// ---------------- kernel D: MFMA GEMM with LDS-coalesced epilogue, fused err ----------------
// Diagnosis r5/6/8: every k_xrec pinned at 2.5 TB/s because the MFMA C/D lane
// layout scatters each Y/Xrec instruction over 16 t-rows (16 x 64 B segments).
// Fix: block = 64t x 256n (4 waves side-by-side in n). Per 16-t slice, acc is
// staged to a block-wide [16][256] f32 LDS tile (XOR-quad swizzle, bank-dense
// both directions), then read back ROW-major: one wave instruction = one
// contiguous 1 KiB span of a single t-row for Y load, diff, and Xrec store.
__global__ __launch_bounds__(256) void k_xrec(const unsigned short* __restrict__ xpk,
                                              const unsigned short* __restrict__ upk,
                                              const float* __restrict__ Y,
                                              float* __restrict__ Xrec,
                                              double* __restrict__ acc_g,
                                              int* __restrict__ cnt,
                                              float* __restrict__ out_tail) {
  __shared__ float stage[16 * 256];   // 16 KiB
  __shared__ float red[512];

  int tid = threadIdx.x;
  int l = tid & 63, w = tid >> 6;
  int lr = l & 15, lg = l >> 4;
  int nt = blockIdx.x & 15;           // 16 n-tiles of 256
  int tt = blockIdx.x >> 4;           // 128 t-tiles of 64
  int n0 = nt * 256, t0 = tt * 64;
  int xtb = t0 >> 4;                  // X tile16 base (+m)
  int unb = (n0 >> 4) + w * 4;        // U tile16 base for this wave (+nf)

  float sd = 0.f, sy = 0.f;

  #pragma unroll
  for (int m = 0; m < 4; ++m) {
    // X frags for this 16-t slice (hi k0, hi k32, lo k0, lo k32)
    bf16x8 a0 = ldfrag(xpk, xtb + m, 0,  lg, lr);
    bf16x8 a1 = ldfrag(xpk, xtb + m, 4,  lg, lr);
    bf16x8 a2 = ldfrag(xpk, xtb + m, 8,  lg, lr);
    bf16x8 a3 = ldfrag(xpk, xtb + m, 12, lg, lr);

    f32x4 acc[4];
    #pragma unroll
    for (int nf = 0; nf < 4; ++nf) {
      bf16x8 u0 = ldfrag(upk, unb + nf, 0,  lg, lr);  // U hi k0
      bf16x8 u1 = ldfrag(upk, unb + nf, 4,  lg, lr);  // U hi k32
      bf16x8 u2 = ldfrag(upk, unb + nf, 8,  lg, lr);  // U lo k0
      bf16x8 u3 = ldfrag(upk, unb + nf, 12, lg, lr);  // U lo k32
      f32x4 a = (f32x4){0.f, 0.f, 0.f, 0.f};
      a = MFMA(u0, a0, a);     // hi*hi k0
      a = MFMA(u1, a1, a);     // hi*hi k32
      a = MFMA(u0, a2, a);     // x_lo * u_hi
      a = MFMA(u1, a3, a);
      a = MFMA(u2, a0, a);     // x_hi * u_lo
      a = MFMA(u3, a1, a);
      acc[nf] = a;
    }

    // stage slice: acc[nf] -> lds[row=lr][colq = w*16+nf*4+lg], XOR-swizzled
    #pragma unroll
    for (int nf = 0; nf < 4; ++nf) {
      int colq = w * 16 + nf * 4 + lg;
      int physq = (colq & 48) | ((colq & 15) ^ lr);
      *(f32x4*)(stage + lr * 256 + physq * 4) = acc[nf];
    }
    __syncthreads();

    // read back row-major: instruction = 1 full row segment (1 KiB contiguous)
    #pragma unroll
    for (int i = 0; i < 4; ++i) {
      int row = i * 4 + w;
      int physq = (l & 48) | ((l & 15) ^ row);
      f32x4 x = *(const f32x4*)(stage + row * 256 + physq * 4);
      size_t gidx = (size_t)(t0 + m * 16 + row) * N_DIM + n0 + l * 4;
      float4 y = *(const float4*)(Y + gidx);
      float d;
      d = y.x - x[0]; sd += d * d; sy += y.x * y.x;
      d = y.y - x[1]; sd += d * d; sy += y.y * y.y;
      d = y.z - x[2]; sd += d * d; sy += y.z * y.z;
      d = y.w - x[3]; sd += d * d; sy += y.w * y.w;
      *(f32x4*)(Xrec + gidx) = x;
    }
    __syncthreads();
  }

  red[tid] = sd; red[256 + tid] = sy;
  __syncthreads();
  for (int s2 = 128; s2 > 0; s2 >>= 1) {
    if (tid < s2) { red[tid] += red[tid + s2]; red[256 + tid] += red[256 + tid + s2]; }
    __syncthreads();
  }
  if (tid == 0) {
    atomicAdd(acc_g,     (double)red[0]);
    atomicAdd(acc_g + 1, (double)red[256]);
    __threadfence();
    int done = atomicAdd(cnt, 1);
    if (done == 2047) {                       // last block finalizes err
      double s0 = atomicAdd(acc_g, 0.0);
      double s1 = atomicAdd(acc_g + 1, 0.0);
      out_tail[0] = (float)sqrt(s0 / s1);
    }
  }
}

extern "C" void kernel_launch(void* const* d_in, const int* in_sizes, int n_in,
                              void* d_out, int out_size, void* d_ws, size_t ws_size,
                              hipStream_t stream) {
  const float* X_train = (const float*)d_in[1];
  const float* Y       = (const float*)d_in[2];
  const float* temp    = (const float*)d_in[3];
  const float* phi     = (const float*)d_in[4];
  const float* A_tilde = (const float*)d_in[5];
  const float* U       = (const float*)d_in[6];
  const float* logits  = (const float*)d_in[7];
  float* out = (float*)d_out;
  float* out_tail = out + (size_t)T_DIM * N_DIM;

  // workspace layout (bytes)
  char* w = (char*)d_ws;
  double* acc          = (double*)w;                     // @0, 16 B
  int* cnt             = (int*)(w + 32);                 // 4 B
  float* Wm            = (float*)(w + 64);               // 13*16384 B -> ends 213056
  float* xh0           = (float*)(w + 213056);           // 256 B
  float* part          = (float*)(w + 213312);           // 16384 B -> ends 229696
  unsigned short* upk  = (unsigned short*)(w + 262144);  // 1 MiB packed U frags
  unsigned short* xpk  = (unsigned short*)(w + 1310720); // 2 MiB packed X frags -> ends 3407872

  k_init<<<272, 256, 0, stream>>>(U, X_train, part, acc, cnt, upk);
  k_prep<<<1, 256, 0, stream>>>(A_tilde, phi, logits, temp, part, Wm, xh0, out_tail);
  k_states<<<N_CHUNK, 64, 0, stream>>>(Wm, xh0, xpk);
  k_xrec<<<2048, 256, 0, stream>>>(xpk, upk, Y, out, acc, cnt, out_tail);
}

// Round 12
// 203.947 us; speedup vs baseline: 1.0175x; 1.0175x over previous
//
#include <hip/hip_runtime.h>
#include <math.h>

// Problem constants
#define T_DIM 8192
#define N_DIM 4096
#define L 64
#define P 32
#define IN_DIM 192
#define S_CHUNK 16
#define N_CHUNK (T_DIM / S_CHUNK)   // 512
#define LDST 68                     // padded LDS row stride (float4-aligned)

using f32x4   = __attribute__((ext_vector_type(4))) float;
using bf16x8  = __attribute__((ext_vector_type(8))) short;
using ushort8 = __attribute__((ext_vector_type(8))) unsigned short;

__device__ __forceinline__ unsigned short f2bf(float x) {
  unsigned u = __float_as_uint(x);
  u += 0x7fffu + ((u >> 16) & 1u);           // round-to-nearest-even
  return (unsigned short)(u >> 16);
}
__device__ __forceinline__ float bf2f(unsigned short h) {
  return __uint_as_float(((unsigned)h) << 16);
}

// Packed fragment layout (both X and U):
//   pk[tile16][g][lane] = 8 bf16 of row (tile16*16 + lane), k-chunk g
//   g in 0..15: g<8 -> hi bits of k=8g..; g>=8 -> lo residual.
// One wave fragment load = contiguous 1 KiB from L2.
__device__ __forceinline__ bf16x8 ldfrag(const unsigned short* __restrict__ base,
                                         int tile16, int gb, int lg, int lr) {
  return *(const bf16x8*)(base + ((size_t)((tile16 * 16 + gb + lg) * 16 + lr)) * 8);
}

#define MFMA(A, B, C) __builtin_amdgcn_mfma_f32_16x16x32_bf16(A, B, C, 0, 0, 0)

// ---------------- kernel A (merged): xh0 partials + U split + scratch init ----------------
__global__ __launch_bounds__(256) void k_init(const float* __restrict__ U,
                                              const float* __restrict__ Xtr,
                                              float* __restrict__ part,
                                              double* __restrict__ acc,
                                              int* __restrict__ cnt,
                                              unsigned short* __restrict__ upk) {
  int blk = blockIdx.x, tid = threadIdx.x;
  if (blk < 16) {
    if (blk == 0) {
      if (tid < 2) acc[tid] = 0.0;
      if (tid == 2) *cnt = 0;
    }
    int b = blk * 4 + (tid >> 6);
    int l = tid & 63;
    int n0 = b * 64;
    float s = 0.f;
    #pragma unroll 8
    for (int i = 0; i < 64; ++i) {
      float x = Xtr[n0 + i];
      s += U[(size_t)(n0 + i) * L + l] * x;
    }
    part[b * 64 + l] = s;
  } else {
    int idx = (blk - 16) * 256 + tid;         // 0 .. 65535
    int lr = idx & 15, g = (idx >> 4) & 15, nn16 = idx >> 8;
    int n = nn16 * 16 + lr;
    int k0 = (g & 7) * 8;
    float4 a = *(const float4*)(U + (size_t)n * L + k0);
    float4 b = *(const float4*)(U + (size_t)n * L + k0 + 4);
    ushort8 o;
    float v[8] = {a.x, a.y, a.z, a.w, b.x, b.y, b.z, b.w};
    #pragma unroll
    for (int j = 0; j < 8; ++j) {
      unsigned short h = f2bf(v[j]);
      o[j] = (g < 8) ? h : f2bf(v[j] - bf2f(h));
    }
    *(ushort8*)(upk + (size_t)idx * 8) = o;
  }
}

// ---------------- kernel B: argmax, temp, build M, xh0, matrix doublings ----------------
__global__ __launch_bounds__(256, 1) void k_prep(const float* __restrict__ A_tilde,
                                                 const float* __restrict__ phi_bar_t,
                                                 const float* __restrict__ logits,
                                                 const float* __restrict__ temp,
                                                 const float* __restrict__ part,
                                                 float* __restrict__ Wm,
                                                 float* __restrict__ xh0,
                                                 float* __restrict__ out_tail) {
  __shared__ float buf[2][64 * LDST];   // 34816 B
  __shared__ float sphi[P * L];         // 8192 B
  __shared__ float spart[4 * 64];       // 1024 B
  __shared__ int   sel_s[P];
  int tid = threadIdx.x;

  #pragma unroll
  for (int i = 0; i < 4; ++i) {
    int f = tid + 256 * i;
    int r = f >> 4, q = f & 15;
    float4 v = ((const float4*)A_tilde)[f];
    *(float4*)(buf[0] + r * LDST + q * 4) = v;
  }
  #pragma unroll
  for (int i = 0; i < 2; ++i) {
    int f = tid + 256 * i;
    ((float4*)sphi)[f] = ((const float4*)phi_bar_t)[f];
  }
  {
    int l = tid & 63, q = tid >> 6;
    float s = 0.f;
    #pragma unroll
    for (int i = 0; i < 16; ++i)
      s += part[(q * 16 + i) * 64 + l];
    spart[q * 64 + l] = s;
  }
  {
    int p = tid >> 3, d = tid & 7;
    const float* row = logits + p * IN_DIM;
    float best = -1e30f; int bk = 0;
    #pragma unroll
    for (int j = 0; j < 6; ++j) {
      int kb = (j * 8 + d) * 4;
      float4 v = *(const float4*)(row + kb);
      if (v.x > best) { best = v.x; bk = kb; }
      if (v.y > best) { best = v.y; bk = kb + 1; }
      if (v.z > best) { best = v.z; bk = kb + 2; }
      if (v.w > best) { best = v.w; bk = kb + 3; }
    }
    #pragma unroll
    for (int off = 4; off > 0; off >>= 1) {
      float vo = __shfl_down(best, off, 8);
      int   ko = __shfl_down(bk,   off, 8);
      if (vo > best || (vo == best && ko < bk)) { best = vo; bk = ko; }
    }
    if (d == 0) {
      sel_s[p] = bk;
      out_tail[2 + p] = (float)bk;
    }
  }
  if (tid == 255) out_tail[1] = fmaxf(0.01f, temp[0] * 0.999f);
  __syncthreads();

  if (tid < L) {
    #pragma unroll 4
    for (int p = 0; p < P; ++p) {
      int kk = sel_s[p]; if (kk > L - 1) kk = L - 1;
      buf[0][tid * LDST + kk] += sphi[p * L + tid];
    }
  } else if (tid < 128) {
    int l = tid - 64;
    xh0[l] = spart[l] + spart[64 + l] + spart[128 + l] + spart[192 + l];
  }
  __syncthreads();

  #pragma unroll
  for (int i = 0; i < 4; ++i) {
    int f = tid + 256 * i;
    int r = f >> 4, q = f & 15;
    *(float4*)(Wm + r * 64 + q * 4) = *(const float4*)(buf[0] + r * LDST + q * 4);
  }

  int r0 = (tid >> 4) << 2;
  int c0 = (tid & 15) << 2;
  int cur = 0;
  for (int j = 1; j <= 12; ++j) {
    const float* S = buf[cur];
    float* D = buf[cur ^ 1];
    float acc[4][4];
    #pragma unroll
    for (int i = 0; i < 4; ++i)
      #pragma unroll
      for (int c = 0; c < 4; ++c) acc[i][c] = 0.f;

    #pragma unroll
    for (int kb = 0; kb < 64; kb += 16) {
      float a[4][16];
      #pragma unroll
      for (int i = 0; i < 4; ++i)
        #pragma unroll
        for (int q = 0; q < 4; ++q) {
          float4 t4 = *(const float4*)(S + (r0 + i) * LDST + kb + q * 4);
          a[i][q * 4 + 0] = t4.x; a[i][q * 4 + 1] = t4.y;
          a[i][q * 4 + 2] = t4.z; a[i][q * 4 + 3] = t4.w;
        }
      #pragma unroll
      for (int kk = 0; kk < 16; ++kk) {
        float4 b4 = *(const float4*)(S + (kb + kk) * LDST + c0);
        #pragma unroll
        for (int i = 0; i < 4; ++i) {
          acc[i][0] += a[i][kk] * b4.x;
          acc[i][1] += a[i][kk] * b4.y;
          acc[i][2] += a[i][kk] * b4.z;
          acc[i][3] += a[i][kk] * b4.w;
        }
      }
    }
    #pragma unroll
    for (int i = 0; i < 4; ++i) {
      float4 o = {acc[i][0], acc[i][1], acc[i][2], acc[i][3]};
      *(float4*)(D + (r0 + i) * LDST + c0) = o;
      *(float4*)(Wm + j * 4096 + (r0 + i) * 64 + c0) = o;
    }
    __syncthreads();
    cur ^= 1;
  }
}

// ---------------- kernel C: states via checkpoints; emit PACKED bf16 hi/lo frags ----------------
__global__ __launch_bounds__(64) void k_states(const float* __restrict__ Wm,
                                               const float* __restrict__ xh0,
                                               unsigned short* __restrict__ xpk) {
  __shared__ float sx[16 * LDST];
  int c = blockIdx.x;
  int l = threadIdx.x;
  float v = xh0[l];
  int e = c << 4;
  for (int j = 4; j <= 12; ++j) {
    if ((e >> j) & 1) {
      const float* W = Wm + j * 4096;
      float n0 = 0.f, n1 = 0.f, n2 = 0.f, n3 = 0.f;
      #pragma unroll
      for (int k = 0; k < 64; k += 4) {
        n0 += W[l * 64 + k]     * __shfl(v, k, 64);
        n1 += W[l * 64 + k + 1] * __shfl(v, k + 1, 64);
        n2 += W[l * 64 + k + 2] * __shfl(v, k + 2, 64);
        n3 += W[l * 64 + k + 3] * __shfl(v, k + 3, 64);
      }
      v = (n0 + n1) + (n2 + n3);
    }
  }
  float m[64];
  #pragma unroll
  for (int k = 0; k < 64; ++k) m[k] = Wm[l * 64 + k];
  for (int i = 0; i < S_CHUNK; ++i) {
    float n0 = 0.f, n1 = 0.f, n2 = 0.f, n3 = 0.f;
    #pragma unroll
    for (int k = 0; k < 64; k += 4) {
      n0 += m[k]     * __shfl(v, k, 64);
      n1 += m[k + 1] * __shfl(v, k + 1, 64);
      n2 += m[k + 2] * __shfl(v, k + 2, 64);
      n3 += m[k + 3] * __shfl(v, k + 3, 64);
    }
    v = (n0 + n1) + (n2 + n3);
    sx[i * LDST + l] = v;
  }
  __syncthreads();

  #pragma unroll
  for (int it = 0; it < 4; ++it) {
    int idx = l + 64 * it;
    int lr = idx & 15, g = idx >> 4;
    int k0 = (g & 7) * 8;
    float4 a = *(const float4*)(sx + lr * LDST + k0);
    float4 b = *(const float4*)(sx + lr * LDST + k0 + 4);
    float vv[8] = {a.x, a.y, a.z, a.w, b.x, b.y, b.z, b.w};
    ushort8 o;
    #pragma unroll
    for (int j = 0; j < 8; ++j) {
      unsigned short h = f2bf(vv[j]);
      o[j] = (g < 8) ? h : f2bf(vv[j] - bf2f(h));
    }
    *(ushort8*)(xpk + ((size_t)c * 256 + idx) * 8) = o;
  }
}

// ---------------- kernel D: MFMA GEMM, LDS-coalesced epilogue, hoisted+pinned loads ----------------
// Round-11 failure: U frags reloaded per m-slice (64 redundant L2 loads/wave)
// and compiler sank all loads to uses (VGPR=52, serial ~500cyc chains, 1 TB/s).
// Fix: (a) 16 U frags loaded ONCE per wave, load cluster pinned with
// sched_barrier(0) so the scheduler cannot sink them; (b) per slice only 4 X
// frag loads remain; (c) keep the [16][256] XOR-swizzled LDS stage (0 bank
// conflicts measured) so Y/Xrec I/O is 1 contiguous KiB per wave instruction.
__global__ __launch_bounds__(256) void k_xrec(const unsigned short* __restrict__ xpk,
                                              const unsigned short* __restrict__ upk,
                                              const float* __restrict__ Y,
                                              float* __restrict__ Xrec,
                                              double* __restrict__ acc_g,
                                              int* __restrict__ cnt,
                                              float* __restrict__ out_tail) {
  __shared__ float stage[16 * 256];   // 16 KiB
  __shared__ float red[512];

  int tid = threadIdx.x;
  int l = tid & 63, w = tid >> 6;
  int lr = l & 15, lg = l >> 4;
  int nt = blockIdx.x & 15;           // 16 n-tiles of 256
  int tt = blockIdx.x >> 4;           // 128 t-tiles of 64
  int n0 = nt * 256, t0 = tt * 64;
  int xtb = t0 >> 4;                  // X tile16 base (+m)
  int unb = (n0 >> 4) + w * 4;        // U tile16 base for this wave (+nf)

  // ---- hoist all 16 U frags (reused by all 4 m-slices), pin with sched_barrier ----
  bf16x8 uf[4][4];
  #pragma unroll
  for (int nf = 0; nf < 4; ++nf) {
    uf[nf][0] = ldfrag(upk, unb + nf, 0,  lg, lr);
    uf[nf][1] = ldfrag(upk, unb + nf, 4,  lg, lr);
    uf[nf][2] = ldfrag(upk, unb + nf, 8,  lg, lr);
    uf[nf][3] = ldfrag(upk, unb + nf, 12, lg, lr);
  }
  __builtin_amdgcn_sched_barrier(0);

  float sd = 0.f, sy = 0.f;

  #pragma unroll
  for (int m = 0; m < 4; ++m) {
    // X frags for this 16-t slice
    bf16x8 a0 = ldfrag(xpk, xtb + m, 0,  lg, lr);
    bf16x8 a1 = ldfrag(xpk, xtb + m, 4,  lg, lr);
    bf16x8 a2 = ldfrag(xpk, xtb + m, 8,  lg, lr);
    bf16x8 a3 = ldfrag(xpk, xtb + m, 12, lg, lr);

    f32x4 acc[4];
    #pragma unroll
    for (int nf = 0; nf < 4; ++nf) {
      f32x4 a = (f32x4){0.f, 0.f, 0.f, 0.f};
      a = MFMA(uf[nf][0], a0, a);     // hi*hi k0
      a = MFMA(uf[nf][1], a1, a);     // hi*hi k32
      a = MFMA(uf[nf][0], a2, a);     // x_lo * u_hi
      a = MFMA(uf[nf][1], a3, a);
      a = MFMA(uf[nf][2], a0, a);     // x_hi * u_lo
      a = MFMA(uf[nf][3], a1, a);
      acc[nf] = a;
    }

    // stage slice: acc[nf] -> lds[row=lr][colq = w*16+nf*4+lg], XOR-swizzled
    #pragma unroll
    for (int nf = 0; nf < 4; ++nf) {
      int colq = w * 16 + nf * 4 + lg;
      int physq = (colq & 48) | ((colq & 15) ^ lr);
      *(f32x4*)(stage + lr * 256 + physq * 4) = acc[nf];
    }
    __syncthreads();

    // read back row-major: one wave instruction = contiguous 1 KiB of one t-row
    #pragma unroll
    for (int i = 0; i < 4; ++i) {
      int row = i * 4 + w;
      int physq = (l & 48) | ((l & 15) ^ row);
      f32x4 x = *(const f32x4*)(stage + row * 256 + physq * 4);
      size_t gidx = (size_t)(t0 + m * 16 + row) * N_DIM + n0 + l * 4;
      float4 y = *(const float4*)(Y + gidx);
      float d;
      d = y.x - x[0]; sd += d * d; sy += y.x * y.x;
      d = y.y - x[1]; sd += d * d; sy += y.y * y.y;
      d = y.z - x[2]; sd += d * d; sy += y.z * y.z;
      d = y.w - x[3]; sd += d * d; sy += y.w * y.w;
      *(f32x4*)(Xrec + gidx) = x;
    }
    __syncthreads();
  }

  red[tid] = sd; red[256 + tid] = sy;
  __syncthreads();
  for (int s2 = 128; s2 > 0; s2 >>= 1) {
    if (tid < s2) { red[tid] += red[tid + s2]; red[256 + tid] += red[256 + tid + s2]; }
    __syncthreads();
  }
  if (tid == 0) {
    atomicAdd(acc_g,     (double)red[0]);
    atomicAdd(acc_g + 1, (double)red[256]);
    __threadfence();
    int done = atomicAdd(cnt, 1);
    if (done == 2047) {                       // last block finalizes err
      double s0 = atomicAdd(acc_g, 0.0);
      double s1 = atomicAdd(acc_g + 1, 0.0);
      out_tail[0] = (float)sqrt(s0 / s1);
    }
  }
}

extern "C" void kernel_launch(void* const* d_in, const int* in_sizes, int n_in,
                              void* d_out, int out_size, void* d_ws, size_t ws_size,
                              hipStream_t stream) {
  const float* X_train = (const float*)d_in[1];
  const float* Y       = (const float*)d_in[2];
  const float* temp    = (const float*)d_in[3];
  const float* phi     = (const float*)d_in[4];
  const float* A_tilde = (const float*)d_in[5];
  const float* U       = (const float*)d_in[6];
  const float* logits  = (const float*)d_in[7];
  float* out = (float*)d_out;
  float* out_tail = out + (size_t)T_DIM * N_DIM;

  // workspace layout (bytes)
  char* w = (char*)d_ws;
  double* acc          = (double*)w;                     // @0, 16 B
  int* cnt             = (int*)(w + 32);                 // 4 B
  float* Wm            = (float*)(w + 64);               // 13*16384 B -> ends 213056
  float* xh0           = (float*)(w + 213056);           // 256 B
  float* part          = (float*)(w + 213312);           // 16384 B -> ends 229696
  unsigned short* upk  = (unsigned short*)(w + 262144);  // 1 MiB packed U frags
  unsigned short* xpk  = (unsigned short*)(w + 1310720); // 2 MiB packed X frags -> ends 3407872

  k_init<<<272, 256, 0, stream>>>(U, X_train, part, acc, cnt, upk);
  k_prep<<<1, 256, 0, stream>>>(A_tilde, phi, logits, temp, part, Wm, xh0, out_tail);
  k_states<<<N_CHUNK, 64, 0, stream>>>(Wm, xh0, xpk);
  k_xrec<<<2048, 256, 0, stream>>>(xpk, upk, Y, out, acc, cnt, out_tail);
}

// Round 13
// 202.973 us; speedup vs baseline: 1.0224x; 1.0048x over previous
//
#include <hip/hip_runtime.h>
#include <math.h>

// Problem constants
#define T_DIM 8192
#define N_DIM 4096
#define L 64
#define P 32
#define IN_DIM 192
#define S_CHUNK 16
#define N_CHUNK (T_DIM / S_CHUNK)   // 512
#define LDST 68                     // padded LDS row stride (float4-aligned)

using f32x4   = __attribute__((ext_vector_type(4))) float;
using bf16x8  = __attribute__((ext_vector_type(8))) short;
using ushort8 = __attribute__((ext_vector_type(8))) unsigned short;

__device__ __forceinline__ unsigned short f2bf(float x) {
  unsigned u = __float_as_uint(x);
  u += 0x7fffu + ((u >> 16) & 1u);           // round-to-nearest-even
  return (unsigned short)(u >> 16);
}
__device__ __forceinline__ float bf2f(unsigned short h) {
  return __uint_as_float(((unsigned)h) << 16);
}

#define MFMA(A, B, C) __builtin_amdgcn_mfma_f32_16x16x32_bf16(A, B, C, 0, 0, 0)

// ---------------- kernel A (merged): xh0 partials + U hi/lo split + scratch init ----------------
__global__ __launch_bounds__(256) void k_init(const float* __restrict__ U,
                                              const float* __restrict__ Xtr,
                                              float* __restrict__ part,
                                              double* __restrict__ acc,
                                              int* __restrict__ cnt,
                                              unsigned short* __restrict__ uh,
                                              unsigned short* __restrict__ ul) {
  int blk = blockIdx.x, tid = threadIdx.x;
  if (blk < 16) {
    if (blk == 0) {
      if (tid < 2) acc[tid] = 0.0;
      if (tid == 2) *cnt = 0;
    }
    int b = blk * 4 + (tid >> 6);
    int l = tid & 63;
    int n0 = b * 64;
    float s = 0.f;
    #pragma unroll 8
    for (int i = 0; i < 64; ++i) {
      float x = Xtr[n0 + i];
      s += U[(size_t)(n0 + i) * L + l] * x;
    }
    part[b * 64 + l] = s;
  } else {
    // U split into bf16 hi/lo, [n][k] layout (float4 vectorized)
    int i = (blk - 16) * 256 + tid;           // 0..16383 float4s
    float4 x = ((const float4*)U)[i];
    ushort4 h, lo;
    h.x = f2bf(x.x); lo.x = f2bf(x.x - bf2f(h.x));
    h.y = f2bf(x.y); lo.y = f2bf(x.y - bf2f(h.y));
    h.z = f2bf(x.z); lo.z = f2bf(x.z - bf2f(h.z));
    h.w = f2bf(x.w); lo.w = f2bf(x.w - bf2f(h.w));
    ((ushort4*)uh)[i] = h;
    ((ushort4*)ul)[i] = lo;
  }
}

// ---------------- kernel B: argmax, temp, build M, xh0, matrix doublings ----------------
__global__ __launch_bounds__(256, 1) void k_prep(const float* __restrict__ A_tilde,
                                                 const float* __restrict__ phi_bar_t,
                                                 const float* __restrict__ logits,
                                                 const float* __restrict__ temp,
                                                 const float* __restrict__ part,
                                                 float* __restrict__ Wm,
                                                 float* __restrict__ xh0,
                                                 float* __restrict__ out_tail) {
  __shared__ float buf[2][64 * LDST];   // 34816 B
  __shared__ float sphi[P * L];         // 8192 B
  __shared__ float spart[4 * 64];       // 1024 B
  __shared__ int   sel_s[P];
  int tid = threadIdx.x;

  #pragma unroll
  for (int i = 0; i < 4; ++i) {
    int f = tid + 256 * i;
    int r = f >> 4, q = f & 15;
    float4 v = ((const float4*)A_tilde)[f];
    *(float4*)(buf[0] + r * LDST + q * 4) = v;
  }
  #pragma unroll
  for (int i = 0; i < 2; ++i) {
    int f = tid + 256 * i;
    ((float4*)sphi)[f] = ((const float4*)phi_bar_t)[f];
  }
  {
    int l = tid & 63, q = tid >> 6;
    float s = 0.f;
    #pragma unroll
    for (int i = 0; i < 16; ++i)
      s += part[(q * 16 + i) * 64 + l];
    spart[q * 64 + l] = s;
  }
  {
    int p = tid >> 3, d = tid & 7;
    const float* row = logits + p * IN_DIM;
    float best = -1e30f; int bk = 0;
    #pragma unroll
    for (int j = 0; j < 6; ++j) {
      int kb = (j * 8 + d) * 4;
      float4 v = *(const float4*)(row + kb);
      if (v.x > best) { best = v.x; bk = kb; }
      if (v.y > best) { best = v.y; bk = kb + 1; }
      if (v.z > best) { best = v.z; bk = kb + 2; }
      if (v.w > best) { best = v.w; bk = kb + 3; }
    }
    #pragma unroll
    for (int off = 4; off > 0; off >>= 1) {
      float vo = __shfl_down(best, off, 8);
      int   ko = __shfl_down(bk,   off, 8);
      if (vo > best || (vo == best && ko < bk)) { best = vo; bk = ko; }
    }
    if (d == 0) {
      sel_s[p] = bk;
      out_tail[2 + p] = (float)bk;
    }
  }
  if (tid == 255) out_tail[1] = fmaxf(0.01f, temp[0] * 0.999f);
  __syncthreads();

  if (tid < L) {
    #pragma unroll 4
    for (int p = 0; p < P; ++p) {
      int kk = sel_s[p]; if (kk > L - 1) kk = L - 1;
      buf[0][tid * LDST + kk] += sphi[p * L + tid];
    }
  } else if (tid < 128) {
    int l = tid - 64;
    xh0[l] = spart[l] + spart[64 + l] + spart[128 + l] + spart[192 + l];
  }
  __syncthreads();

  #pragma unroll
  for (int i = 0; i < 4; ++i) {
    int f = tid + 256 * i;
    int r = f >> 4, q = f & 15;
    *(float4*)(Wm + r * 64 + q * 4) = *(const float4*)(buf[0] + r * LDST + q * 4);
  }

  int r0 = (tid >> 4) << 2;
  int c0 = (tid & 15) << 2;
  int cur = 0;
  for (int j = 1; j <= 12; ++j) {
    const float* S = buf[cur];
    float* D = buf[cur ^ 1];
    float acc[4][4];
    #pragma unroll
    for (int i = 0; i < 4; ++i)
      #pragma unroll
      for (int c = 0; c < 4; ++c) acc[i][c] = 0.f;

    #pragma unroll
    for (int kb = 0; kb < 64; kb += 16) {
      float a[4][16];
      #pragma unroll
      for (int i = 0; i < 4; ++i)
        #pragma unroll
        for (int q = 0; q < 4; ++q) {
          float4 t4 = *(const float4*)(S + (r0 + i) * LDST + kb + q * 4);
          a[i][q * 4 + 0] = t4.x; a[i][q * 4 + 1] = t4.y;
          a[i][q * 4 + 2] = t4.z; a[i][q * 4 + 3] = t4.w;
        }
      #pragma unroll
      for (int kk = 0; kk < 16; ++kk) {
        float4 b4 = *(const float4*)(S + (kb + kk) * LDST + c0);
        #pragma unroll
        for (int i = 0; i < 4; ++i) {
          acc[i][0] += a[i][kk] * b4.x;
          acc[i][1] += a[i][kk] * b4.y;
          acc[i][2] += a[i][kk] * b4.z;
          acc[i][3] += a[i][kk] * b4.w;
        }
      }
    }
    #pragma unroll
    for (int i = 0; i < 4; ++i) {
      float4 o = {acc[i][0], acc[i][1], acc[i][2], acc[i][3]};
      *(float4*)(D + (r0 + i) * LDST + c0) = o;
      *(float4*)(Wm + j * 4096 + (r0 + i) * 64 + c0) = o;
    }
    __syncthreads();
    cur ^= 1;
  }
}

// ---------------- kernel C: states via checkpoints, emit bf16 hi/lo [t][k] ----------------
__global__ __launch_bounds__(64) void k_states(const float* __restrict__ Wm,
                                               const float* __restrict__ xh0,
                                               unsigned short* __restrict__ xhi,
                                               unsigned short* __restrict__ xlo) {
  int c = blockIdx.x;       // 512 chunks of 16 steps
  int l = threadIdx.x;
  float v = xh0[l];
  int e = c << 4;
  for (int j = 4; j <= 12; ++j) {
    if ((e >> j) & 1) {
      const float* W = Wm + j * 4096;
      float n0 = 0.f, n1 = 0.f, n2 = 0.f, n3 = 0.f;
      #pragma unroll
      for (int k = 0; k < 64; k += 4) {
        n0 += W[l * 64 + k]     * __shfl(v, k, 64);
        n1 += W[l * 64 + k + 1] * __shfl(v, k + 1, 64);
        n2 += W[l * 64 + k + 2] * __shfl(v, k + 2, 64);
        n3 += W[l * 64 + k + 3] * __shfl(v, k + 3, 64);
      }
      v = (n0 + n1) + (n2 + n3);
    }
  }
  float m[64];
  #pragma unroll
  for (int k = 0; k < 64; ++k) m[k] = Wm[l * 64 + k];
  int t0 = c * S_CHUNK;
  for (int i = 0; i < S_CHUNK; ++i) {
    float n0 = 0.f, n1 = 0.f, n2 = 0.f, n3 = 0.f;
    #pragma unroll
    for (int k = 0; k < 64; k += 4) {
      n0 += m[k]     * __shfl(v, k, 64);
      n1 += m[k + 1] * __shfl(v, k + 1, 64);
      n2 += m[k + 2] * __shfl(v, k + 2, 64);
      n3 += m[k + 3] * __shfl(v, k + 3, 64);
    }
    v = (n0 + n1) + (n2 + n3);
    unsigned short h = f2bf(v);
    unsigned short lo = f2bf(v - bf2f(h));
    size_t base = (size_t)(t0 + i) * L + l;   // [t][k] layout, coalesced
    xhi[base] = h; xlo[base] = lo;
  }
}

// ---------------- kernel D: round-6 MFMA GEMM + LDS-coalesced epilogue, fused err ----------------
// GEMM phase is round-6 verbatim (LDS-staged operands -> ds_read feeds MFMA;
// immune to the load-sinking pathology that serialized rounds 9-12, measured
// 83 us). New: after MFMA the SAME 64 KiB smem becomes a [128][128] f32 stage
// (XOR-quad swizzle, write 8dw/bank, read 4dw/bank - both optimal). Read-back
// is row-major: one wave instruction = two contiguous 512-B spans of Y/Xrec
// (vs 16 scattered 64-B segments before) - tests the DRAM-granularity theory.
__global__ __launch_bounds__(256, 2) void k_xrec(const unsigned short* __restrict__ xhi,
                                                 const unsigned short* __restrict__ xlo,
                                                 const unsigned short* __restrict__ uh,
                                                 const unsigned short* __restrict__ ul,
                                                 const float* __restrict__ Y,
                                                 float* __restrict__ Xrec,
                                                 double* __restrict__ acc_g,
                                                 int* __restrict__ cnt,
                                                 float* __restrict__ out_tail) {
  __shared__ __align__(16) unsigned char smem[65536];   // Xs|Us, then f32 stage
  __shared__ float red[512];
  unsigned short* Xs = (unsigned short*)smem;           // 32 KiB
  unsigned short* Us = (unsigned short*)(smem + 32768); // 32 KiB
  float* stage = (float*)smem;                          // 64 KiB (after MFMA)

  int tid = threadIdx.x;
  int nt = blockIdx.x & 31, tt = blockIdx.x >> 5;
  int n0 = nt * 128, t0 = tt * 128;

  // stage A-tile: row t = [xhi[t0+t][0..63] | xlo[t0+t][0..63]]
  #pragma unroll
  for (int i = 0; i < 8; ++i) {
    int c = tid + 256 * i;
    int t = c >> 4, p = c & 15;
    const ushort8* src = (p < 8)
      ? (const ushort8*)(xhi + (size_t)(t0 + t) * L + p * 8)
      : (const ushort8*)(xlo + (size_t)(t0 + t) * L + (p - 8) * 8);
    *(ushort8*)((char*)Xs + t * 256 + ((p * 16) ^ ((t & 7) << 4))) = *src;
  }
  // stage B-tile: row n = [uh[n0+n][0..63] | ul[n0+n][0..63]]
  #pragma unroll
  for (int i = 0; i < 8; ++i) {
    int c = tid + 256 * i;
    int nn = c >> 4, p = c & 15;
    const ushort8* src = (p < 8)
      ? (const ushort8*)(uh + (size_t)(n0 + nn) * L + p * 8)
      : (const ushort8*)(ul + (size_t)(n0 + nn) * L + (p - 8) * 8);
    *(ushort8*)((char*)Us + nn * 256 + ((p * 16) ^ ((nn & 7) << 4))) = *src;
  }
  __syncthreads();

  int l = tid & 63, wid = tid >> 6;
  int wr = wid >> 1, wc = wid & 1;
  int lr = l & 15, lg = l >> 4;

  f32x4 acc[4][4];
  #pragma unroll
  for (int m = 0; m < 4; ++m)
    #pragma unroll
    for (int nf = 0; nf < 4; ++nf) acc[m][nf] = (f32x4){0.f, 0.f, 0.f, 0.f};

  // k-step plan: s0,1 = hi*hi (k 0..63); s2,3 = lo*hi; s4,5 = hi*lo
  const int KA[6] = {0, 32, 64, 96, 0, 32};
  const int KB[6] = {0, 32, 0, 32, 64, 96};
  #pragma unroll
  for (int s = 0; s < 6; ++s) {
    bf16x8 af[4], bfr[4];
    #pragma unroll
    for (int m = 0; m < 4; ++m) {
      int t_loc = wr * 64 + m * 16 + lr;
      int kk = KA[s] + lg * 8;
      af[m] = *(const bf16x8*)((const char*)Xs + t_loc * 256 + ((kk * 2) ^ ((t_loc & 7) << 4)));
    }
    #pragma unroll
    for (int nf = 0; nf < 4; ++nf) {
      int n_loc = wc * 64 + nf * 16 + lr;
      int kk = KB[s] + lg * 8;
      bfr[nf] = *(const bf16x8*)((const char*)Us + n_loc * 256 + ((kk * 2) ^ ((n_loc & 7) << 4)));
    }
    // swapped operands: D 4-reg axis = n (contiguous)
    #pragma unroll
    for (int m = 0; m < 4; ++m)
      #pragma unroll
      for (int nf = 0; nf < 4; ++nf)
        acc[m][nf] = MFMA(bfr[nf], af[m], acc[m][nf]);
  }
  __syncthreads();   // all ds_reads done; safe to overwrite smem as stage

  // ---- stage acc into [128][128] f32, XOR-quad swizzle ----
  // lane's acc[m][nf] = 4 consecutive n at t_loc; logical (t_loc, nq*4..nq*4+3)
  #pragma unroll
  for (int m = 0; m < 4; ++m) {
    int t_loc = wr * 64 + m * 16 + lr;
    #pragma unroll
    for (int nf = 0; nf < 4; ++nf) {
      int nq = wc * 16 + nf * 4 + lg;
      int physq = nq ^ (t_loc & 31);
      *(f32x4*)(stage + t_loc * 128 + physq * 4) = acc[m][nf];
    }
  }
  __syncthreads();

  // ---- streaming epilogue: row-major, 2 x 512-B contiguous spans per wave instr ----
  float sd = 0.f, sy = 0.f;
  #pragma unroll
  for (int p = 0; p < 16; ++p) {
    int flat = p * 1024 + tid * 4;
    int row = flat >> 7;               // 0..127
    int nq2 = (flat >> 2) & 31;
    int physq = nq2 ^ (row & 31);
    f32x4 x = *(const f32x4*)(stage + row * 128 + physq * 4);
    size_t gidx = (size_t)(t0 + row) * N_DIM + n0 + nq2 * 4;
    float4 y = *(const float4*)(Y + gidx);
    float d;
    d = y.x - x[0]; sd += d * d; sy += y.x * y.x;
    d = y.y - x[1]; sd += d * d; sy += y.y * y.y;
    d = y.z - x[2]; sd += d * d; sy += y.z * y.z;
    d = y.w - x[3]; sd += d * d; sy += y.w * y.w;
    *(f32x4*)(Xrec + gidx) = x;
  }

  red[tid] = sd; red[256 + tid] = sy;
  __syncthreads();
  for (int s2 = 128; s2 > 0; s2 >>= 1) {
    if (tid < s2) { red[tid] += red[tid + s2]; red[256 + tid] += red[256 + tid + s2]; }
    __syncthreads();
  }
  if (tid == 0) {
    atomicAdd(acc_g,     (double)red[0]);
    atomicAdd(acc_g + 1, (double)red[256]);
    __threadfence();
    int done = atomicAdd(cnt, 1);
    if (done == 2047) {                       // last block finalizes err
      double s0 = atomicAdd(acc_g, 0.0);
      double s1 = atomicAdd(acc_g + 1, 0.0);
      out_tail[0] = (float)sqrt(s0 / s1);
    }
  }
}

extern "C" void kernel_launch(void* const* d_in, const int* in_sizes, int n_in,
                              void* d_out, int out_size, void* d_ws, size_t ws_size,
                              hipStream_t stream) {
  const float* X_train = (const float*)d_in[1];
  const float* Y       = (const float*)d_in[2];
  const float* temp    = (const float*)d_in[3];
  const float* phi     = (const float*)d_in[4];
  const float* A_tilde = (const float*)d_in[5];
  const float* U       = (const float*)d_in[6];
  const float* logits  = (const float*)d_in[7];
  float* out = (float*)d_out;
  float* out_tail = out + (size_t)T_DIM * N_DIM;

  // workspace layout (bytes)
  char* w = (char*)d_ws;
  double* acc          = (double*)w;                     // @0, 16 B
  int* cnt             = (int*)(w + 32);                 // 4 B
  float* Wm            = (float*)(w + 64);               // 13*16384 B -> ends 213056
  float* xh0           = (float*)(w + 213056);           // 256 B
  float* part          = (float*)(w + 213312);           // 16384 B -> ends 229696
  unsigned short* uh   = (unsigned short*)(w + 262144);  // 512 KiB
  unsigned short* ul   = (unsigned short*)(w + 786432);  // 512 KiB
  unsigned short* xhi  = (unsigned short*)(w + 1310720); // 1 MiB
  unsigned short* xlo  = (unsigned short*)(w + 2359296); // 1 MiB -> ends 3407872

  k_init<<<80, 256, 0, stream>>>(U, X_train, part, acc, cnt, uh, ul);
  k_prep<<<1, 256, 0, stream>>>(A_tilde, phi, logits, temp, part, Wm, xh0, out_tail);
  k_states<<<N_CHUNK, 64, 0, stream>>>(Wm, xh0, xhi, xlo);
  k_xrec<<<2048, 256, 0, stream>>>(xhi, xlo, uh, ul, Y, out, acc, cnt, out_tail);
}